// Round 4
// baseline (902.825 us; speedup 1.0000x reference)
//
#include <hip/hip_runtime.h>

// Fused deformable 2D conv, fp32. B=8 H=128 W=128 C=64 F=128 K=3 pad=1.
// One block = 32 pixels of one row. No workspace used.
// Phase 0a: stage zero-padded x halo (3 rows x 34 cols x 64c) into LDS.
// Phase 0b: offset conv: offs[pix][t] = sum_{p,q,c} xtile * oW[p][q][c][t].
// Phase 1 : bilinear column gather -> smp[32][576] (stride 580).
// Phase 2 : out[32][128] = smp @ cW + cb, register-tiled 4 pix x 4 f.
//
// R4 fix: per-batch stride of x is 128*128*64 = 2^20 (was wrongly <<19 in
// R1-R3 -> batches 1..7 read misaligned data, absmax ~6.5).

#define SMP_STR 580

__device__ __forceinline__ float vget(const float4 v, int d) {
  return d == 0 ? v.x : d == 1 ? v.y : d == 2 ? v.z : v.w;
}

__global__ __launch_bounds__(256) void fused_deform_kernel(
    const float* __restrict__ x, const float* __restrict__ oW,
    const float* __restrict__ ob, const float* __restrict__ cW,
    const float* __restrict__ cb, float* __restrict__ out) {
  __shared__ float smp[32 * SMP_STR];  // 74240 B; phase 0 reuses as xtile
  __shared__ float offs_s[32 * 9];
  const int tid = threadIdx.x;
  const int bid = blockIdx.x;
  const int j0 = (bid & 3) << 5;   // 4 strips of 32 pixels per row
  const int i = (bid >> 2) & 127;
  const int b = bid >> 9;
  const float* xb = x + ((size_t)b << 20);  // b * 128*128*64 = b * 2^20

  // ---- Phase 0a: xtile[r][cc][c], r=i-1..i+1, cc = j0-1..j0+32, zero-pad ----
  float* xtile = smp;  // 3*34*64 = 6528 floats
  for (int t = tid; t < 3 * 34 * 16; t += 256) {
    const int c4 = t & 15;
    const int cc = (t >> 4) % 34;
    const int r = (t >> 4) / 34;
    const int row = i + r - 1;
    const int col = j0 + cc - 1;
    float4 v = make_float4(0.f, 0.f, 0.f, 0.f);
    if (row >= 0 && row <= 127 && col >= 0 && col <= 127)
      v = ((const float4*)(xb + (((row << 7) + col) << 6)))[c4];
    *(float4*)(xtile + (((r * 34 + cc) << 6) + (c4 << 2))) = v;
  }
  __syncthreads();

  // ---- Phase 0b: offsets. offs_s[pix][t] = ob[t]
  //      + sum over ALL 9 kernel taps (p,q) and 64 channels c.            ----
  for (int t = tid; t < 288; t += 256) {
    const int ochan = t % 9;
    const int pix = t / 9;
    float acc = ob[ochan];
#pragma unroll
    for (int p = 0; p < 3; ++p) {
#pragma unroll
      for (int q = 0; q < 3; ++q) {
        const float* xr = xtile + ((p * 34 + pix + q) << 6);   // zero-padded
        const float* wr = oW + (p * 3 + q) * 576 + ochan;      // [p][q][c][t]
        for (int c = 0; c < 64; ++c) acc += xr[c] * wr[c * 9];
      }
    }
    offs_s[t] = acc;
  }
  __syncthreads();  // all xtile reads done before smp is overwritten

  // ---- Phase 1: bilinear gather into smp[pix][tap*64 + c] ----
  for (int it = tid; it < 32 * 9 * 16; it += 256) {
    const int c4 = it & 15;
    const int tmp = it >> 4;  // 0..287
    const int tap = tmp % 9;
    const int pix = tmp / 9;
    const int j = j0 + pix;
    const float off = offs_s[pix * 9 + tap];
    const int p = tap / 3;
    const int q = tap - p * 3;
    int yy = i + p - 1;                       // row: clamped
    yy = yy < 0 ? 0 : (yy > 127 ? 127 : yy);
    const float xf = (float)(j + q - 1) + off;
    const float x0f = floorf(xf);
    const float w1 = xf - x0f;                // weight from UNclipped floor
    int x0i = (int)x0f;
    x0i = x0i < 0 ? 0 : (x0i > 127 ? 127 : x0i);
    const int x1i = (x0i + 1 > 127) ? 127 : x0i + 1;
    const float4 s0 = ((const float4*)(xb + (((yy << 7) + x0i) << 6)))[c4];
    const float4 s1 = ((const float4*)(xb + (((yy << 7) + x1i) << 6)))[c4];
    const float w0 = 1.0f - w1;
    float4 r;
    r.x = s0.x * w0 + s1.x * w1;
    r.y = s0.y * w0 + s1.y * w1;
    r.z = s0.z * w0 + s1.z * w1;
    r.w = s0.w * w0 + s1.w * w1;
    *(float4*)(smp + pix * SMP_STR + tap * 64 + (c4 << 2)) = r;
  }
  __syncthreads();

  // ---- Phase 2: out[pix][f] = sum_k smp[pix][k] * cW[k][f] + cb[f] ----
  const int fg = tid & 31;            // f block of 4: f = fg*4..fg*4+3
  const int pbase = (tid >> 5) << 2;  // 4 pixels per thread
  float4 acc[4];
#pragma unroll
  for (int pp = 0; pp < 4; ++pp) acc[pp] = make_float4(0.f, 0.f, 0.f, 0.f);
  const float4* cw4 = (const float4*)cW;  // [k][f/4]: cw4[k*32 + fg]

  for (int k = 0; k < 576; k += 4) {
    float4 s[4];
#pragma unroll
    for (int pp = 0; pp < 4; ++pp)
      s[pp] = *(const float4*)(smp + (pbase + pp) * SMP_STR + k);
#pragma unroll
    for (int d = 0; d < 4; ++d) {
      const float4 w = cw4[(size_t)(k + d) * 32 + fg];
#pragma unroll
      for (int pp = 0; pp < 4; ++pp) {
        const float sv = vget(s[pp], d);
        acc[pp].x += sv * w.x;
        acc[pp].y += sv * w.y;
        acc[pp].z += sv * w.z;
        acc[pp].w += sv * w.w;
      }
    }
  }

  const float4 bias = ((const float4*)cb)[fg];
#pragma unroll
  for (int pp = 0; pp < 4; ++pp) {
    float4 r;
    r.x = acc[pp].x + bias.x;
    r.y = acc[pp].y + bias.y;
    r.z = acc[pp].z + bias.z;
    r.w = acc[pp].w + bias.w;
    const size_t row = (size_t)((((b << 7) | i) << 7) | (j0 + pbase + pp));
    ((float4*)out)[row * 32 + fg] = r;
  }
}

extern "C" void kernel_launch(void* const* d_in, const int* in_sizes, int n_in,
                              void* d_out, int out_size, void* d_ws, size_t ws_size,
                              hipStream_t stream) {
  const float* x = (const float*)d_in[0];
  const float* oW = (const float*)d_in[1];
  const float* ob = (const float*)d_in[2];
  const float* cW = (const float*)d_in[3];
  const float* cb = (const float*)d_in[4];
  float* out = (float*)d_out;

  hipLaunchKernelGGL(fused_deform_kernel, dim3(4096), dim3(256), 0, stream,
                     x, oW, ob, cW, cb, out);
}

// Round 6
// 467.533 us; speedup vs baseline: 1.9310x; 1.9310x over previous
//
#include <hip/hip_runtime.h>

// Fused deformable 2D conv. B=8 H=128 W=128 C=64 F=128 K=3 pad=1.
// One block = 32 pixels of one row, 256 threads = 4 waves. No workspace.
// Phase 0a: stage zero-padded x halo fp32 [3*34 rows][68 stride] in LDS
//           (68 mod 32 = 4 -> conflict-free float4 reads across pixels).
// Phase 0b: offset conv in fp32 VALU (bf16 offsets flip floor() at the
//           xf<0 clamp discontinuities -> must match reference precision).
// Phase 1 : bilinear gather (fp32 math) -> smpB bf16 [32][576], XOR-swizzled.
// Phase 2 : out[32][128] = smpB @ cW + cb via bf16 MFMA 16x16x32.
//           Wave w owns f in [32w,32w+32): 2 m-tiles x 2 n-tiles.
//
// MFMA 16x16x32 bf16 layouts (HW-verified m89/m91):
//   A: row=lane&15, k=8*(lane>>4)+j (8 contig bf16)
//   B: col=lane&15, k=8*(lane>>4)+j
//   C: col=lane&15, row=4*(lane>>4)+reg
// xtile fp32 (27744 B) aliases smpB (36864 B): dead before phase 1 writes.

typedef __attribute__((ext_vector_type(8))) short short8;
typedef __attribute__((ext_vector_type(4))) float f32x4;

__device__ __forceinline__ unsigned short f2bf(float f) {  // RNE
  union { float f; unsigned u; } v; v.f = f;
  unsigned r = v.u + 0x7fffu + ((v.u >> 16) & 1u);
  return (unsigned short)(r >> 16);
}

__global__ __launch_bounds__(256, 4) void fused_deform_kernel(
    const float* __restrict__ x, const float* __restrict__ oW,
    const float* __restrict__ ob, const float* __restrict__ cW,
    const float* __restrict__ cb, float* __restrict__ out) {
  __shared__ __align__(16) char lds[32 * 576 * 2];  // 36864 B (smpB / xtile)
  __shared__ float offs_s[32 * 9];
  unsigned short* const smpB = (unsigned short*)lds;
  float* const xtile = (float*)lds;  // [102 rows][stride 68 floats]

  const int tid = threadIdx.x;
  const int bid = blockIdx.x;
  const int j0 = (bid & 3) << 5;
  const int i = (bid >> 2) & 127;
  const int b = bid >> 9;
  const float* xb = x + ((size_t)b << 20);  // batch stride 2^20 floats

  const int lane = tid & 63;
  const int wv = tid >> 6;

  // ---- Phase 0a: fp32 x halo, rows r*34+cc (r=0..2, cc=0..33), stride 68 --
  for (int t = tid; t < 3 * 34 * 16; t += 256) {
    const int c4 = t & 15;
    const int cc = (t >> 4) % 34;
    const int r = (t >> 4) / 34;
    const int row = i + r - 1;
    const int col = j0 + cc - 1;
    float4 v = make_float4(0.f, 0.f, 0.f, 0.f);
    if (row >= 0 && row <= 127 && col >= 0 && col <= 127)
      v = ((const float4*)(xb + (((row << 7) + col) << 6)))[c4];
    *(float4*)(xtile + (r * 34 + cc) * 68 + c4 * 4) = v;
  }
  __syncthreads();

  // ---- Phase 0b: offsets fp32. offs_s[pix*9+t] = ob[t] + sum_{p,q,c} -----
  for (int t = tid; t < 288; t += 256) {
    const int ochan = t % 9;
    const int pix = t / 9;
    float acc = ob[ochan];
#pragma unroll
    for (int p = 0; p < 3; ++p) {
#pragma unroll
      for (int q = 0; q < 3; ++q) {
        const float* xr = xtile + (p * 34 + pix + q) * 68;
        const float* wr = oW + (p * 3 + q) * 576 + ochan;  // [p][q][c][t]
        for (int c4 = 0; c4 < 16; ++c4) {
          const float4 v = *(const float4*)(xr + c4 * 4);
          acc += v.x * wr[(c4 * 4 + 0) * 9] + v.y * wr[(c4 * 4 + 1) * 9] +
                 v.z * wr[(c4 * 4 + 2) * 9] + v.w * wr[(c4 * 4 + 3) * 9];
        }
      }
    }
    offs_s[t] = acc;
  }
  __syncthreads();  // xtile dead from here; smpB takes over the buffer

  // ---- Phase 1: bilinear gather -> smpB bf16 (fp32 math, matches ref) ----
  for (int it = tid; it < 32 * 9 * 16; it += 256) {
    const int c4 = it & 15;
    const int tmp = it >> 4;
    const int tap = tmp % 9;
    const int pix = tmp / 9;
    const int j = j0 + pix;
    const float off = offs_s[pix * 9 + tap];
    const int p = tap / 3;
    const int q = tap - p * 3;
    int yy = i + p - 1;
    yy = yy < 0 ? 0 : (yy > 127 ? 127 : yy);
    const float xf = (float)(j + q - 1) + off;
    const float x0f = floorf(xf);
    const float w1 = xf - x0f;            // weight from UNclipped floor
    int x0i = (int)x0f;
    x0i = x0i < 0 ? 0 : (x0i > 127 ? 127 : x0i);
    const int x1i = (x0i + 1 > 127) ? 127 : x0i + 1;
    const float4 s0 = ((const float4*)(xb + (((yy << 7) + x0i) << 6)))[c4];
    const float4 s1 = ((const float4*)(xb + (((yy << 7) + x1i) << 6)))[c4];
    const float w0 = 1.0f - w1;
    const int boff = (pix * 1152 + tap * 128 + c4 * 8) ^ ((pix & 7) << 4);
    uint2 pk;
    pk.x = (unsigned)f2bf(s0.x * w0 + s1.x * w1) |
           ((unsigned)f2bf(s0.y * w0 + s1.y * w1) << 16);
    pk.y = (unsigned)f2bf(s0.z * w0 + s1.z * w1) |
           ((unsigned)f2bf(s0.w * w0 + s1.w * w1) << 16);
    *(uint2*)(lds + boff) = pk;
  }
  __syncthreads();

  // ---- Phase 2: out = smpB @ cW + cb (wave w: f in [32w, 32w+32)) ----
  const int f0 = wv << 5;
  const int colf = lane & 15;
  const int kg = lane >> 4;
  f32x4 a00 = {0.f, 0.f, 0.f, 0.f}, a01 = a00, a10 = a00, a11 = a00;
  const float* wbase = cW + f0 + colf;
  for (int ks = 0; ks < 18; ++ks) {
    const int aoff0 = (colf * 1152 + ks * 64 + kg * 16) ^ ((colf & 7) << 4);
    const short8 af0 = *(const short8*)(lds + aoff0);
    const short8 af1 = *(const short8*)(lds + aoff0 + 16 * 1152);
    const float* wp = wbase + (size_t)(ks * 32 + kg * 8) * 128;
    short8 bf0, bf1;
#pragma unroll
    for (int jj = 0; jj < 8; ++jj) bf0[jj] = (short)f2bf(wp[jj * 128]);
#pragma unroll
    for (int jj = 0; jj < 8; ++jj) bf1[jj] = (short)f2bf(wp[jj * 128 + 16]);
    a00 = __builtin_amdgcn_mfma_f32_16x16x32_bf16(af0, bf0, a00, 0, 0, 0);
    a01 = __builtin_amdgcn_mfma_f32_16x16x32_bf16(af0, bf1, a01, 0, 0, 0);
    a10 = __builtin_amdgcn_mfma_f32_16x16x32_bf16(af1, bf0, a10, 0, 0, 0);
    a11 = __builtin_amdgcn_mfma_f32_16x16x32_bf16(af1, bf1, a11, 0, 0, 0);
  }

  const float cb0 = cb[f0 + colf];
  const float cb1 = cb[f0 + 16 + colf];
  float* obase = out + (((size_t)((b << 14) | (i << 7) | j0)) << 7);
#pragma unroll
  for (int reg = 0; reg < 4; ++reg) {
    float* r0 = obase + (size_t)(kg * 4 + reg) * 128;       // pixels 0..15
    r0[f0 + colf] = a00[reg] + cb0;
    r0[f0 + 16 + colf] = a01[reg] + cb1;
    float* r1 = obase + (size_t)(16 + kg * 4 + reg) * 128;  // pixels 16..31
    r1[f0 + colf] = a10[reg] + cb0;
    r1[f0 + 16 + colf] = a11[reg] + cb1;
  }
}

extern "C" void kernel_launch(void* const* d_in, const int* in_sizes, int n_in,
                              void* d_out, int out_size, void* d_ws, size_t ws_size,
                              hipStream_t stream) {
  const float* x = (const float*)d_in[0];
  const float* oW = (const float*)d_in[1];
  const float* ob = (const float*)d_in[2];
  const float* cW = (const float*)d_in[3];
  const float* cb = (const float*)d_in[4];
  float* out = (float*)d_out;

  hipLaunchKernelGGL(fused_deform_kernel, dim3(4096), dim3(256), 0, stream,
                     x, oW, ob, cW, cb, out);
}

// Round 7
// 361.444 us; speedup vs baseline: 2.4978x; 1.2935x over previous
//
#include <hip/hip_runtime.h>

// Fused deformable 2D conv. B=8 H=128 W=128 C=64 F=128 K=3 pad=1.
// Main kernel: one block = 32 pixels of one row, 512 threads = 8 waves.
// Pack kernel (one-shot, ~170KB ws): cW fp32 -> cWb bf16 in MFMA B-frag
//   order [ks18][q4 4][f 128][jj 8]; oW -> oWt fp32 [ochan 9][pq 9][c 64].
// Phase 0a: zero-padded x halo fp32 [102 rows][stride 68] in LDS.
// Phase 0b: offset conv fp32 VALU (bf16 offsets would flip floor() at the
//   clamp discontinuities). 2 lanes/item, float4 acc chains, shfl reduce.
// Phase 1 : bilinear gather (fp32 math) -> smpB bf16 [32][576], XOR-swizzled.
// Phase 2 : out[32][128] via MFMA 16x16x32. Wave w: m-tile w&1, f0=(w>>1)*32,
//   2 n-tiles. B-frags are single 16B loads from cWb.
//
// MFMA 16x16x32 bf16 (HW-verified m89/m91): A row=lane&15, k=8*(lane>>4)+j;
// B col=lane&15 same k; C col=lane&15, row=4*(lane>>4)+reg.
// xtile fp32 (27.7KB) aliases smpB (36.9KB): xtile dead before phase 1.

typedef __attribute__((ext_vector_type(8))) short short8;
typedef __attribute__((ext_vector_type(4))) float f32x4;

#define CWB_BYTES (18 * 4 * 128 * 8 * 2)        // 147456
#define OWT_OFF   CWB_BYTES
#define WS_NEED   (CWB_BYTES + 9 * 9 * 64 * 4)  // +20736 = 168192

__device__ __forceinline__ unsigned short f2bf(float f) {  // RNE
  union { float f; unsigned u; } v; v.f = f;
  unsigned r = v.u + 0x7fffu + ((v.u >> 16) & 1u);
  return (unsigned short)(r >> 16);
}

__global__ __launch_bounds__(256) void pack_weights(
    const float* __restrict__ cW, const float* __restrict__ oW,
    unsigned short* __restrict__ cWb, float* __restrict__ oWt) {
  const int t = blockIdx.x * 256 + threadIdx.x;
  if (t < 73728) {  // t = k*128 + f
    const int k = t >> 7, f = t & 127;
    const int ks = k >> 5, q4 = (k >> 3) & 3, jj = k & 7;
    cWb[(size_t)(((ks * 4 + q4) * 128 + f) * 8 + jj)] = f2bf(cW[t]);
  }
  if (t < 5184) {  // oWt[(ochan*9+pq)*64+c] = oW[(pq*64+c)*9+ochan]
    const int ochan = t % 9, rest = t / 9;
    const int pq = rest >> 6, c = rest & 63;
    oWt[(ochan * 9 + pq) * 64 + c] = oW[(size_t)(pq * 64 + c) * 9 + ochan];
  }
}

template <bool PACKED>
__global__ __launch_bounds__(512, 8) void fused_deform_kernel(
    const float* __restrict__ x, const float* __restrict__ oW,
    const float* __restrict__ ob, const float* __restrict__ cW,
    const float* __restrict__ cb, float* __restrict__ out,
    const unsigned short* __restrict__ cWb, const float* __restrict__ oWt) {
  __shared__ __align__(16) char lds[32 * 576 * 2];  // 36864 B (smpB / xtile)
  __shared__ float offs_s[288];
  float* const xtile = (float*)lds;  // [102 rows][stride 68 floats]

  const int tid = threadIdx.x;
  const int bid = blockIdx.x;
  const int j0 = (bid & 3) << 5;
  const int i = (bid >> 2) & 127;
  const int b = bid >> 9;
  const float* xb = x + ((size_t)b << 20);  // batch stride 2^20 floats

  const int lane = tid & 63;
  const int wv = tid >> 6;

  // ---- Phase 0a: fp32 x halo, rows r*34+cc, stride 68 (conflict-free) ----
  for (int t = tid; t < 3 * 34 * 16; t += 512) {
    const int c4 = t & 15;
    const int cc = (t >> 4) % 34;
    const int r = (t >> 4) / 34;
    const int row = i + r - 1;
    const int col = j0 + cc - 1;
    float4 v = make_float4(0.f, 0.f, 0.f, 0.f);
    if (row >= 0 && row <= 127 && col >= 0 && col <= 127)
      v = ((const float4*)(xb + (((row << 7) + col) << 6)))[c4];
    *(float4*)(xtile + (r * 34 + cc) * 68 + c4 * 4) = v;
  }
  __syncthreads();

  // ---- Phase 0b: offsets fp32. 2 lanes/item (c-halves), shfl_xor reduce ---
  for (int t = tid; t < 576; t += 512) {
    const int half = t & 1;
    const int item = t >> 1;          // pix*9 + ochan
    const int ochan = item % 9;
    const int pix = item / 9;
    const int c4base = half << 3;     // 0 or 8 (8 float4s each)
    f32x4 acc = {0.f, 0.f, 0.f, 0.f};
#pragma unroll
    for (int pq = 0; pq < 9; ++pq) {
      const int p = pq / 3, q = pq - p * 3;
      const float4* xr = (const float4*)(xtile + (p * 34 + pix + q) * 68) + c4base;
      if (PACKED) {
        const float4* wr = (const float4*)(oWt + (ochan * 9 + pq) * 64) + c4base;
#pragma unroll
        for (int c4 = 0; c4 < 8; ++c4) {
          const float4 v = xr[c4];
          const float4 w = wr[c4];
          acc.x += v.x * w.x; acc.y += v.y * w.y;
          acc.z += v.z * w.z; acc.w += v.w * w.w;
        }
      } else {
        const float* wr = oW + (size_t)(pq * 64 + c4base * 4) * 9 + ochan;
#pragma unroll
        for (int c4 = 0; c4 < 8; ++c4) {
          const float4 v = xr[c4];
          acc.x += v.x * wr[(c4 * 4 + 0) * 9];
          acc.y += v.y * wr[(c4 * 4 + 1) * 9];
          acc.z += v.z * wr[(c4 * 4 + 2) * 9];
          acc.w += v.w * wr[(c4 * 4 + 3) * 9];
        }
      }
    }
    float s = (acc.x + acc.y) + (acc.z + acc.w);
    s += __shfl_xor(s, 1);
    if (!half) offs_s[item] = s + ob[ochan];
  }
  __syncthreads();  // xtile dead from here; smpB takes over the buffer

  // ---- Phase 1: bilinear gather -> smpB bf16 (fp32 math, matches ref) ----
  for (int it = tid; it < 32 * 9 * 16; it += 512) {
    const int c4 = it & 15;
    const int tmp = it >> 4;
    const int tap = tmp % 9;
    const int pix = tmp / 9;
    const int j = j0 + pix;
    const float off = offs_s[pix * 9 + tap];
    const int p = tap / 3;
    const int q = tap - p * 3;
    int yy = i + p - 1;
    yy = yy < 0 ? 0 : (yy > 127 ? 127 : yy);
    const float xf = (float)(j + q - 1) + off;
    const float x0f = floorf(xf);
    const float w1 = xf - x0f;            // weight from UNclipped floor
    int x0i = (int)x0f;
    x0i = x0i < 0 ? 0 : (x0i > 127 ? 127 : x0i);
    const int x1i = (x0i + 1 > 127) ? 127 : x0i + 1;
    const float4 s0 = ((const float4*)(xb + (((yy << 7) + x0i) << 6)))[c4];
    const float4 s1 = ((const float4*)(xb + (((yy << 7) + x1i) << 6)))[c4];
    const float w0 = 1.0f - w1;
    const int boff = (pix * 1152 + tap * 128 + c4 * 8) ^ ((pix & 7) << 4);
    uint2 pk;
    pk.x = (unsigned)f2bf(s0.x * w0 + s1.x * w1) |
           ((unsigned)f2bf(s0.y * w0 + s1.y * w1) << 16);
    pk.y = (unsigned)f2bf(s0.z * w0 + s1.z * w1) |
           ((unsigned)f2bf(s0.w * w0 + s1.w * w1) << 16);
    *(uint2*)(lds + boff) = pk;
  }
  __syncthreads();

  // ---- Phase 2: MFMA. Wave w: m-tile m=w&1 (pixels 16m..), f0=(w>>1)*32 ---
  const int m = wv & 1;
  const int f0 = (wv >> 1) << 5;
  const int colf = lane & 15;
  const int q4 = lane >> 4;
  const int pix = m * 16 + colf;
  f32x4 a0 = {0.f, 0.f, 0.f, 0.f}, a1 = a0;
  for (int ks = 0; ks < 18; ++ks) {
    const int aoff = (pix * 1152 + ks * 64 + q4 * 16) ^ ((pix & 7) << 4);
    const short8 af = *(const short8*)(lds + aoff);
    short8 bf0, bf1;
    if (PACKED) {
      const unsigned short* wb = cWb + (size_t)(((ks * 4 + q4) * 128 + f0 + colf) * 8);
      bf0 = *(const short8*)wb;
      bf1 = *(const short8*)(wb + 16 * 8);
    } else {
      const float* wp = cW + (size_t)(ks * 32 + q4 * 8) * 128 + f0 + colf;
#pragma unroll
      for (int jj = 0; jj < 8; ++jj) bf0[jj] = (short)f2bf(wp[jj * 128]);
#pragma unroll
      for (int jj = 0; jj < 8; ++jj) bf1[jj] = (short)f2bf(wp[jj * 128 + 16]);
    }
    a0 = __builtin_amdgcn_mfma_f32_16x16x32_bf16(af, bf0, a0, 0, 0, 0);
    a1 = __builtin_amdgcn_mfma_f32_16x16x32_bf16(af, bf1, a1, 0, 0, 0);
  }

  const float cb0 = cb[f0 + colf];
  const float cb1 = cb[f0 + 16 + colf];
  float* obase = out + (((size_t)((b << 14) | (i << 7) | j0)) << 7);
#pragma unroll
  for (int reg = 0; reg < 4; ++reg) {
    float* r = obase + (size_t)(m * 16 + q4 * 4 + reg) * 128;
    r[f0 + colf] = a0[reg] + cb0;
    r[f0 + 16 + colf] = a1[reg] + cb1;
  }
}

extern "C" void kernel_launch(void* const* d_in, const int* in_sizes, int n_in,
                              void* d_out, int out_size, void* d_ws, size_t ws_size,
                              hipStream_t stream) {
  const float* x = (const float*)d_in[0];
  const float* oW = (const float*)d_in[1];
  const float* ob = (const float*)d_in[2];
  const float* cW = (const float*)d_in[3];
  const float* cb = (const float*)d_in[4];
  float* out = (float*)d_out;

  if (ws_size >= WS_NEED) {
    unsigned short* cWb = (unsigned short*)d_ws;
    float* oWt = (float*)((char*)d_ws + OWT_OFF);
    hipLaunchKernelGGL(pack_weights, dim3(288), dim3(256), 0, stream,
                       cW, oW, cWb, oWt);
    hipLaunchKernelGGL((fused_deform_kernel<true>), dim3(4096), dim3(512), 0,
                       stream, x, oW, ob, cW, cb, out, cWb, oWt);
  } else {
    hipLaunchKernelGGL((fused_deform_kernel<false>), dim3(4096), dim3(512), 0,
                       stream, x, oW, ob, cW, cb, out, nullptr, nullptr);
  }
}

// Round 8
// 350.548 us; speedup vs baseline: 2.5755x; 1.0311x over previous
//
#include <hip/hip_runtime.h>

// Fused deformable 2D conv. B=8 H=128 W=128 C=64 F=128 K=3 pad=1.
// Block = 32 pixels of one row, 512 threads = 8 waves. Grid 4096, XCD-swizzled
// (logical = (hw&7)*512 + hw>>3 -> XCD k processes batch k; gather working
// set 4.2MB fits per-XCD L2).
// Pack kernel (one-shot, ws): cW -> cWb bf16 A-frag order [ks][q4][f][jj];
//   oW -> oWt fp32 [ochan][pq][c].
// Phase 0a: zero-padded x halo fp32 [102 rows][stride 68] in LDS (batched
//   loads: 4 in flight).
// Phase 0b: offset conv fp32 VALU (bf16 offsets would flip floor() at the
//   clamp discontinuities). 2 lanes/item, float4 chains, shfl reduce.
// Phase 1 : bilinear gather -> smpB bf16 [32][576] XOR-swizzled. 3-item
//   batches, 6 loads in flight.
// Phase 2 : MFMA 16x16x32, swapped operands (A=weights rows=f, B=pixels):
//   D col=pixel, rows=f -> lane holds float4 along f. B-frag prefetch.
// Epilogue: stage out-tile in LDS [32][132], stream coalesced float4 stores.
//
// MFMA 16x16x32 bf16 (m89/m91): A row=lane&15,k=8*(lane>>4)+j; B col=lane&15
// same k; D col=lane&15, row=4*(lane>>4)+reg.

typedef __attribute__((ext_vector_type(8))) short short8;
typedef __attribute__((ext_vector_type(4))) float f32x4;

#define CWB_BYTES (18 * 4 * 128 * 8 * 2)        // 147456
#define OWT_OFF   CWB_BYTES
#define WS_NEED   (CWB_BYTES + 9 * 9 * 64 * 4)  // 168192

__device__ __forceinline__ unsigned short f2bf(float f) {  // RNE
  union { float f; unsigned u; } v; v.f = f;
  unsigned r = v.u + 0x7fffu + ((v.u >> 16) & 1u);
  return (unsigned short)(r >> 16);
}

__global__ __launch_bounds__(256) void pack_weights(
    const float* __restrict__ cW, const float* __restrict__ oW,
    unsigned short* __restrict__ cWb, float* __restrict__ oWt) {
  const int t = blockIdx.x * 256 + threadIdx.x;
  if (t < 73728) {  // t = k*128 + f
    const int k = t >> 7, f = t & 127;
    const int ks = k >> 5, q4 = (k >> 3) & 3, jj = k & 7;
    cWb[(size_t)(((ks * 4 + q4) * 128 + f) * 8 + jj)] = f2bf(cW[t]);
  }
  if (t < 5184) {  // oWt[(ochan*9+pq)*64+c] = oW[(pq*64+c)*9+ochan]
    const int ochan = t % 9, rest = t / 9;
    const int pq = rest >> 6, c = rest & 63;
    oWt[(ochan * 9 + pq) * 64 + c] = oW[(size_t)(pq * 64 + c) * 9 + ochan];
  }
}

template <bool PACKED>
__global__ __launch_bounds__(512, 8) void fused_deform_kernel(
    const float* __restrict__ x, const float* __restrict__ oW,
    const float* __restrict__ ob, const float* __restrict__ cW,
    const float* __restrict__ cb, float* __restrict__ out,
    const unsigned short* __restrict__ cWb, const float* __restrict__ oWt) {
  __shared__ __align__(16) char lds[32 * 576 * 2];  // 36864 B
  __shared__ float offs_s[288];
  float* const xtile = (float*)lds;  // [102 rows][stride 68 floats]

  const int tid = threadIdx.x;
  const int hwbid = blockIdx.x;
  const int bid = ((hwbid & 7) << 9) | (hwbid >> 3);  // XCD k -> batch k
  const int j0 = (bid & 3) << 5;
  const int i = (bid >> 2) & 127;
  const int b = bid >> 9;
  const float* xb = x + ((size_t)b << 20);  // batch stride 2^20 floats

  const int lane = tid & 63;
  const int wv = tid >> 6;

  // ---- Phase 0a: fp32 x halo, rows r*34+cc, stride 68; 4 loads in flight --
  {
    float4 vv[4];
    int dst[4];
    bool act[4];
#pragma unroll
    for (int k = 0; k < 4; ++k) {
      const int it = tid + k * 512;
      act[k] = it < 1632;  // 3*34*16
      const int c4 = it & 15;
      const int cc = (it >> 4) % 34;
      const int r = (it >> 4) / 34;
      const int row = i + r - 1;
      const int col = j0 + cc - 1;
      vv[k] = make_float4(0.f, 0.f, 0.f, 0.f);
      dst[k] = (r * 34 + cc) * 68 + c4 * 4;
      if (act[k] && row >= 0 && row <= 127 && col >= 0 && col <= 127)
        vv[k] = ((const float4*)(xb + (((row << 7) + col) << 6)))[c4];
    }
#pragma unroll
    for (int k = 0; k < 4; ++k)
      if (act[k]) *(float4*)(xtile + dst[k]) = vv[k];
  }
  __syncthreads();

  // ---- Phase 0b: offsets fp32. 2 lanes/item (c-halves), shfl_xor reduce ---
  for (int t = tid; t < 576; t += 512) {
    const int half = t & 1;
    const int item = t >> 1;  // pix*9 + ochan
    const int ochan = item % 9;
    const int pix = item / 9;
    const int c4base = half << 3;
    f32x4 acc = {0.f, 0.f, 0.f, 0.f};
#pragma unroll
    for (int pq = 0; pq < 9; ++pq) {
      const int p = pq / 3, q = pq - p * 3;
      const float4* xr = (const float4*)(xtile + (p * 34 + pix + q) * 68) + c4base;
      if (PACKED) {
        const float4* wr = (const float4*)(oWt + (ochan * 9 + pq) * 64) + c4base;
#pragma unroll
        for (int c4 = 0; c4 < 8; ++c4) {
          const float4 v = xr[c4];
          const float4 w = wr[c4];
          acc.x += v.x * w.x; acc.y += v.y * w.y;
          acc.z += v.z * w.z; acc.w += v.w * w.w;
        }
      } else {
        const float* wr = oW + (size_t)(pq * 64 + c4base * 4) * 9 + ochan;
#pragma unroll
        for (int c4 = 0; c4 < 8; ++c4) {
          const float4 v = xr[c4];
          acc.x += v.x * wr[(c4 * 4 + 0) * 9];
          acc.y += v.y * wr[(c4 * 4 + 1) * 9];
          acc.z += v.z * wr[(c4 * 4 + 2) * 9];
          acc.w += v.w * wr[(c4 * 4 + 3) * 9];
        }
      }
    }
    float s = (acc.x + acc.y) + (acc.z + acc.w);
    s += __shfl_xor(s, 1);
    if (!half) offs_s[item] = s + ob[ochan];
  }
  __syncthreads();  // xtile dead; smpB takes over lds

  // ---- Phase 1: bilinear gather -> smpB bf16; 3-item batches, 6 loads -----
#pragma unroll
  for (int batch = 0; batch < 3; ++batch) {
    int g0[3], g1[3], sb[3];
    float sw1[3];
#pragma unroll
    for (int s = 0; s < 3; ++s) {
      const int it = tid + (batch * 3 + s) * 512;
      const int c4 = it & 15;
      const int tmp = it >> 4;
      const int tap = tmp % 9;
      const int pix = tmp / 9;
      const int j = j0 + pix;
      const float off = offs_s[pix * 9 + tap];
      const int p = tap / 3;
      const int q = tap - p * 3;
      int yy = i + p - 1;
      yy = yy < 0 ? 0 : (yy > 127 ? 127 : yy);
      const float xf = (float)(j + q - 1) + off;
      const float x0f = floorf(xf);
      sw1[s] = xf - x0f;  // weight from UNclipped floor
      int x0i = (int)x0f;
      x0i = x0i < 0 ? 0 : (x0i > 127 ? 127 : x0i);
      const int x1i = (x0i + 1 > 127) ? 127 : x0i + 1;
      g0[s] = ((((yy << 7) + x0i) << 6) + (c4 << 2)) << 2;  // byte offsets
      g1[s] = ((((yy << 7) + x1i) << 6) + (c4 << 2)) << 2;
      sb[s] = (pix * 1152 + tap * 128 + c4 * 8) ^ ((pix & 7) << 4);
    }
    float4 s0[3], s1[3];
#pragma unroll
    for (int s = 0; s < 3; ++s) {
      s0[s] = *(const float4*)((const char*)xb + g0[s]);
      s1[s] = *(const float4*)((const char*)xb + g1[s]);
    }
#pragma unroll
    for (int s = 0; s < 3; ++s) {
      const float w1 = sw1[s], w0 = 1.0f - w1;
      uint2 pk;
      pk.x = (unsigned)f2bf(s0[s].x * w0 + s1[s].x * w1) |
             ((unsigned)f2bf(s0[s].y * w0 + s1[s].y * w1) << 16);
      pk.y = (unsigned)f2bf(s0[s].z * w0 + s1[s].z * w1) |
             ((unsigned)f2bf(s0[s].w * w0 + s1[s].w * w1) << 16);
      *(uint2*)(lds + sb[s]) = pk;
    }
  }
  __syncthreads();

  // ---- Phase 2: MFMA, swapped operands. Wave w: m=w&1, f0=(w>>1)*32 -------
  const int m = wv & 1;
  const int f0 = (wv >> 1) << 5;
  const int colf = lane & 15;
  const int q4 = lane >> 4;
  const int pixr = m * 16 + colf;
  f32x4 a0 = {0.f, 0.f, 0.f, 0.f}, a1 = a0;
  short8 bf0, bf1;
  if (PACKED) {
    const unsigned short* wb = cWb + (size_t)((q4 * 128 + f0 + colf) * 8);
    bf0 = *(const short8*)wb;
    bf1 = *(const short8*)(wb + 128);
  } else {
    const float* wp = cW + (size_t)(q4 * 8) * 128 + f0 + colf;
#pragma unroll
    for (int jj = 0; jj < 8; ++jj) bf0[jj] = (short)f2bf(wp[jj * 128]);
#pragma unroll
    for (int jj = 0; jj < 8; ++jj) bf1[jj] = (short)f2bf(wp[jj * 128 + 16]);
  }
  for (int ks = 0; ks < 18; ++ks) {
    const int aoff = (pixr * 1152 + ks * 64 + q4 * 16) ^ ((pixr & 7) << 4);
    const short8 af = *(const short8*)(lds + aoff);
    short8 nb0, nb1;
    if (ks < 17) {
      if (PACKED) {
        const unsigned short* wn =
            cWb + (size_t)((((ks + 1) * 4 + q4) * 128 + f0 + colf) * 8);
        nb0 = *(const short8*)wn;
        nb1 = *(const short8*)(wn + 128);
      } else {
        const float* wp = cW + (size_t)((ks + 1) * 32 + q4 * 8) * 128 + f0 + colf;
#pragma unroll
        for (int jj = 0; jj < 8; ++jj) nb0[jj] = (short)f2bf(wp[jj * 128]);
#pragma unroll
        for (int jj = 0; jj < 8; ++jj) nb1[jj] = (short)f2bf(wp[jj * 128 + 16]);
      }
    }
    a0 = __builtin_amdgcn_mfma_f32_16x16x32_bf16(bf0, af, a0, 0, 0, 0);
    a1 = __builtin_amdgcn_mfma_f32_16x16x32_bf16(bf1, af, a1, 0, 0, 0);
    if (ks < 17) { bf0 = nb0; bf1 = nb1; }
  }
  __syncthreads();  // all phase-2 LDS reads done; reuse lds as out-stage

  // ---- Epilogue: stage [32 pix][132 stride] fp32 tile, coalesced stores ---
  float* const outS = (float*)lds;
  {
    const float4 cb0 = *(const float4*)(cb + f0 + q4 * 4);
    const float4 cb1 = *(const float4*)(cb + f0 + 16 + q4 * 4);
    float4 r0, r1;
    r0.x = a0[0] + cb0.x; r0.y = a0[1] + cb0.y;
    r0.z = a0[2] + cb0.z; r0.w = a0[3] + cb0.w;
    r1.x = a1[0] + cb1.x; r1.y = a1[1] + cb1.y;
    r1.z = a1[2] + cb1.z; r1.w = a1[3] + cb1.w;
    *(float4*)(outS + pixr * 132 + f0 + q4 * 4) = r0;
    *(float4*)(outS + pixr * 132 + f0 + 16 + q4 * 4) = r1;
  }
  __syncthreads();
  float4* og = (float4*)(out + (((size_t)((b << 14) | (i << 7) | j0)) << 7));
#pragma unroll
  for (int r = 0; r < 2; ++r) {
    const int f4i = r * 512 + tid;
    const int pp = f4i >> 5, ff = f4i & 31;
    og[pp * 32 + ff] = *(const float4*)(outS + pp * 132 + ff * 4);
  }
}

extern "C" void kernel_launch(void* const* d_in, const int* in_sizes, int n_in,
                              void* d_out, int out_size, void* d_ws, size_t ws_size,
                              hipStream_t stream) {
  const float* x = (const float*)d_in[0];
  const float* oW = (const float*)d_in[1];
  const float* ob = (const float*)d_in[2];
  const float* cW = (const float*)d_in[3];
  const float* cb = (const float*)d_in[4];
  float* out = (float*)d_out;

  if (ws_size >= WS_NEED) {
    unsigned short* cWb = (unsigned short*)d_ws;
    float* oWt = (float*)((char*)d_ws + OWT_OFF);
    hipLaunchKernelGGL(pack_weights, dim3(288), dim3(256), 0, stream,
                       cW, oW, cWb, oWt);
    hipLaunchKernelGGL((fused_deform_kernel<true>), dim3(4096), dim3(512), 0,
                       stream, x, oW, ob, cW, cb, out, cWb, oWt);
  } else {
    hipLaunchKernelGGL((fused_deform_kernel<false>), dim3(4096), dim3(512), 0,
                       stream, x, oW, ob, cW, cb, out, nullptr, nullptr);
  }
}

// Round 9
// 113.944 us; speedup vs baseline: 7.9234x; 3.0765x over previous
//
#include <hip/hip_runtime.h>

// Deformable 2D conv, split-kernel version. B=8 H=128 W=128 C=64 F=128 K=3.
// K1 pack_weights: cW -> cWb bf16 in MFMA frag order [ks][q4][f][jj].
// K2 offsets_kernel: 1 thread/pixel, 9 acc, FMA:load=36:1, no LDS/barriers.
//    offs[pix][9] -> d_ws. XCD-swizzled (block batch = XCD).
// K3 main kernel: block = 32 pixels of one row, 512 thr = 8 waves.
//    load offs (72 float4) -> gather bf16 smpB[32][576] XOR-swizzled
//    (3-item batches, 6 loads in flight; launch_bounds(512,4) so VGPRs exist)
//    -> MFMA 16x16x32 (swapped operands, B-frag prefetch) -> LDS-staged
//    coalesced epilogue. XCD-swizzled grid.
// Fallback (small ws): R8 fused kernel, unpacked.
//
// MFMA 16x16x32 bf16 (m89/m91): A row=lane&15, k=8*(lane>>4)+j; B col same;
// D col=lane&15, row=4*(lane>>4)+reg.

typedef __attribute__((ext_vector_type(8))) short short8;
typedef __attribute__((ext_vector_type(4))) float f32x4;

#define CWB_BYTES (18 * 4 * 128 * 8 * 2)  // 147456
#define OFFS_OFF  CWB_BYTES
#define OFFS_BYTES (131072 * 9 * 4)       // 4718592
#define WS_SPLIT  (CWB_BYTES + OFFS_BYTES)

__device__ __forceinline__ unsigned short f2bf(float f) {  // RNE
  union { float f; unsigned u; } v; v.f = f;
  unsigned r = v.u + 0x7fffu + ((v.u >> 16) & 1u);
  return (unsigned short)(r >> 16);
}

__global__ __launch_bounds__(256) void pack_weights(
    const float* __restrict__ cW, unsigned short* __restrict__ cWb) {
  const int t = blockIdx.x * 256 + threadIdx.x;
  if (t < 73728) {  // t = k*128 + f
    const int k = t >> 7, f = t & 127;
    const int ks = k >> 5, q4 = (k >> 3) & 3, jj = k & 7;
    cWb[(size_t)(((ks * 4 + q4) * 128 + f) * 8 + jj)] = f2bf(cW[t]);
  }
}

// ---- K2: offsets. 1 thread/pixel, zero-pad SAME conv, 9 accumulators. ----
__global__ __launch_bounds__(256) void offsets_kernel(
    const float* __restrict__ x, const float* __restrict__ oW,
    const float* __restrict__ ob, float* __restrict__ offs) {
  const int hw = blockIdx.x;
  const int logical = ((hw & 7) << 6) | (hw >> 3);  // XCD k -> batch k
  const int pix = logical * 256 + threadIdx.x;      // 0..131071
  const int j = pix & 127;
  const int i = (pix >> 7) & 127;
  const int b = pix >> 14;
  float acc[9];
#pragma unroll
  for (int t = 0; t < 9; ++t) acc[t] = ob[t];
  const float* xb = x + ((size_t)b << 20);
#pragma unroll
  for (int p = 0; p < 3; ++p) {
    const int yy = i + p - 1;
    if (yy < 0 || yy > 127) continue;  // zero padding
#pragma unroll
    for (int q = 0; q < 3; ++q) {
      const int xx = j + q - 1;
      if (xx < 0 || xx > 127) continue;
      const float4* xp = (const float4*)(xb + (((yy << 7) + xx) << 6));
      const float* wp = oW + (p * 3 + q) * 576;  // wave-uniform -> sK$
#pragma unroll 4
      for (int c4 = 0; c4 < 16; ++c4) {
        const float4 v = xp[c4];
        const float* w = wp + c4 * 36;
#pragma unroll
        for (int t = 0; t < 9; ++t) acc[t] += v.x * w[t];
#pragma unroll
        for (int t = 0; t < 9; ++t) acc[t] += v.y * w[9 + t];
#pragma unroll
        for (int t = 0; t < 9; ++t) acc[t] += v.z * w[18 + t];
#pragma unroll
        for (int t = 0; t < 9; ++t) acc[t] += v.w * w[27 + t];
      }
    }
  }
  float* op = offs + (size_t)pix * 9;
#pragma unroll
  for (int t = 0; t < 9; ++t) op[t] = acc[t];
}

// ---- K3: gather + MFMA main conv. ----
__global__ __launch_bounds__(512, 4) void main_kernel(
    const float* __restrict__ x, const float* __restrict__ offs,
    const float* __restrict__ cb, float* __restrict__ out,
    const unsigned short* __restrict__ cWb) {
  __shared__ __align__(16) char lds[32 * 576 * 2];  // 36864 B
  __shared__ float offs_s[288];

  const int tid = threadIdx.x;
  const int hwbid = blockIdx.x;
  const int bid = ((hwbid & 7) << 9) | (hwbid >> 3);  // XCD k -> batch k
  const int j0 = (bid & 3) << 5;
  const int i = (bid >> 2) & 127;
  const int b = bid >> 9;
  const float* xb = x + ((size_t)b << 20);

  const int lane = tid & 63;
  const int wv = tid >> 6;

  // ---- offsets for this block's 32 pixels: 288 contiguous floats ----
  if (tid < 72) {
    const size_t base = ((size_t)(((b << 7) | i) << 7) | j0) * 9;  // /4 ok
    ((float4*)offs_s)[tid] = ((const float4*)(offs + base))[tid];
  }
  __syncthreads();

  // ---- Phase 1: bilinear gather -> smpB bf16; 3-item batches ----
#pragma unroll
  for (int batch = 0; batch < 3; ++batch) {
    int g0[3], g1[3], sb[3];
    float sw1[3];
#pragma unroll
    for (int s = 0; s < 3; ++s) {
      const int it = tid + (batch * 3 + s) * 512;
      const int c4 = it & 15;
      const int tmp = it >> 4;
      const int tap = tmp % 9;
      const int pix = tmp / 9;
      const int j = j0 + pix;
      const float off = offs_s[pix * 9 + tap];
      const int p = tap / 3;
      const int q = tap - p * 3;
      int yy = i + p - 1;
      yy = yy < 0 ? 0 : (yy > 127 ? 127 : yy);
      const float xf = (float)(j + q - 1) + off;
      const float x0f = floorf(xf);
      sw1[s] = xf - x0f;  // weight from UNclipped floor (matches ref)
      int x0i = (int)x0f;
      x0i = x0i < 0 ? 0 : (x0i > 127 ? 127 : x0i);
      const int x1i = (x0i + 1 > 127) ? 127 : x0i + 1;
      g0[s] = ((((yy << 7) + x0i) << 6) + (c4 << 2)) << 2;  // byte offsets
      g1[s] = ((((yy << 7) + x1i) << 6) + (c4 << 2)) << 2;
      sb[s] = (pix * 1152 + tap * 128 + c4 * 8) ^ ((pix & 7) << 4);
    }
    float4 s0[3], s1[3];
#pragma unroll
    for (int s = 0; s < 3; ++s) {
      s0[s] = *(const float4*)((const char*)xb + g0[s]);
      s1[s] = *(const float4*)((const char*)xb + g1[s]);
    }
#pragma unroll
    for (int s = 0; s < 3; ++s) {
      const float w1 = sw1[s], w0 = 1.0f - w1;
      uint2 pk;
      pk.x = (unsigned)f2bf(s0[s].x * w0 + s1[s].x * w1) |
             ((unsigned)f2bf(s0[s].y * w0 + s1[s].y * w1) << 16);
      pk.y = (unsigned)f2bf(s0[s].z * w0 + s1[s].z * w1) |
             ((unsigned)f2bf(s0[s].w * w0 + s1[s].w * w1) << 16);
      *(uint2*)(lds + sb[s]) = pk;
    }
  }
  __syncthreads();

  // ---- Phase 2: MFMA, swapped operands. Wave w: m=w&1, f0=(w>>1)*32 ----
  const int m = wv & 1;
  const int f0 = (wv >> 1) << 5;
  const int colf = lane & 15;
  const int q4 = lane >> 4;
  const int pixr = m * 16 + colf;
  f32x4 a0 = {0.f, 0.f, 0.f, 0.f}, a1 = a0;
  short8 bf0, bf1;
  {
    const unsigned short* wb = cWb + (size_t)((q4 * 128 + f0 + colf) * 8);
    bf0 = *(const short8*)wb;
    bf1 = *(const short8*)(wb + 128);
  }
  for (int ks = 0; ks < 18; ++ks) {
    const int aoff = (pixr * 1152 + ks * 64 + q4 * 16) ^ ((pixr & 7) << 4);
    const short8 af = *(const short8*)(lds + aoff);
    short8 nb0, nb1;
    if (ks < 17) {
      const unsigned short* wn =
          cWb + (size_t)((((ks + 1) * 4 + q4) * 128 + f0 + colf) * 8);
      nb0 = *(const short8*)wn;
      nb1 = *(const short8*)(wn + 128);
    }
    a0 = __builtin_amdgcn_mfma_f32_16x16x32_bf16(bf0, af, a0, 0, 0, 0);
    a1 = __builtin_amdgcn_mfma_f32_16x16x32_bf16(bf1, af, a1, 0, 0, 0);
    if (ks < 17) { bf0 = nb0; bf1 = nb1; }
  }
  __syncthreads();  // phase-2 LDS reads done; reuse lds for out staging

  // ---- Epilogue: stage [32 pix][132] fp32, then coalesced stores ----
  float* const outS = (float*)lds;
  {
    const float4 cb0 = *(const float4*)(cb + f0 + q4 * 4);
    const float4 cb1 = *(const float4*)(cb + f0 + 16 + q4 * 4);
    float4 r0, r1;
    r0.x = a0[0] + cb0.x; r0.y = a0[1] + cb0.y;
    r0.z = a0[2] + cb0.z; r0.w = a0[3] + cb0.w;
    r1.x = a1[0] + cb1.x; r1.y = a1[1] + cb1.y;
    r1.z = a1[2] + cb1.z; r1.w = a1[3] + cb1.w;
    *(float4*)(outS + pixr * 132 + f0 + q4 * 4) = r0;
    *(float4*)(outS + pixr * 132 + f0 + 16 + q4 * 4) = r1;
  }
  __syncthreads();
  float4* og = (float4*)(out + (((size_t)((b << 14) | (i << 7) | j0)) << 7));
#pragma unroll
  for (int r = 0; r < 2; ++r) {
    const int f4i = r * 512 + tid;
    const int pp = f4i >> 5, ff = f4i & 31;
    og[pp * 32 + ff] = *(const float4*)(outS + pp * 132 + ff * 4);
  }
}

// ---- Fallback: fused kernel (R8 semantics, unpacked). ----
__global__ __launch_bounds__(512, 8) void fused_deform_kernel(
    const float* __restrict__ x, const float* __restrict__ oW,
    const float* __restrict__ ob, const float* __restrict__ cW,
    const float* __restrict__ cb, float* __restrict__ out) {
  __shared__ __align__(16) char lds[32 * 576 * 2];
  __shared__ float offs_s[288];
  float* const xtile = (float*)lds;  // [102 rows][stride 68]

  const int tid = threadIdx.x;
  const int bid = blockIdx.x;
  const int j0 = (bid & 3) << 5;
  const int i = (bid >> 2) & 127;
  const int b = bid >> 9;
  const float* xb = x + ((size_t)b << 20);
  const int lane = tid & 63;
  const int wv = tid >> 6;

  for (int t = tid; t < 3 * 34 * 16; t += 512) {
    const int c4 = t & 15;
    const int cc = (t >> 4) % 34;
    const int r = (t >> 4) / 34;
    const int row = i + r - 1;
    const int col = j0 + cc - 1;
    float4 v = make_float4(0.f, 0.f, 0.f, 0.f);
    if (row >= 0 && row <= 127 && col >= 0 && col <= 127)
      v = ((const float4*)(xb + (((row << 7) + col) << 6)))[c4];
    *(float4*)(xtile + (r * 34 + cc) * 68 + c4 * 4) = v;
  }
  __syncthreads();

  for (int t = tid; t < 576; t += 512) {
    const int half = t & 1;
    const int item = t >> 1;
    const int ochan = item % 9;
    const int pix = item / 9;
    const int c4base = half << 3;
    f32x4 acc = {0.f, 0.f, 0.f, 0.f};
#pragma unroll
    for (int pq = 0; pq < 9; ++pq) {
      const int p = pq / 3, q = pq - p * 3;
      const float4* xr = (const float4*)(xtile + (p * 34 + pix + q) * 68) + c4base;
      const float* wr = oW + (size_t)(pq * 64 + c4base * 4) * 9 + ochan;
#pragma unroll
      for (int c4 = 0; c4 < 8; ++c4) {
        const float4 v = xr[c4];
        acc.x += v.x * wr[(c4 * 4 + 0) * 9];
        acc.y += v.y * wr[(c4 * 4 + 1) * 9];
        acc.z += v.z * wr[(c4 * 4 + 2) * 9];
        acc.w += v.w * wr[(c4 * 4 + 3) * 9];
      }
    }
    float s = (acc.x + acc.y) + (acc.z + acc.w);
    s += __shfl_xor(s, 1);
    if (!half) offs_s[item] = s + ob[ochan];
  }
  __syncthreads();

  for (int it = tid; it < 32 * 9 * 16; it += 512) {
    const int c4 = it & 15;
    const int tmp = it >> 4;
    const int tap = tmp % 9;
    const int pix = tmp / 9;
    const int j = j0 + pix;
    const float off = offs_s[pix * 9 + tap];
    const int p = tap / 3;
    const int q = tap - p * 3;
    int yy = i + p - 1;
    yy = yy < 0 ? 0 : (yy > 127 ? 127 : yy);
    const float xf = (float)(j + q - 1) + off;
    const float x0f = floorf(xf);
    const float w1 = xf - x0f;
    int x0i = (int)x0f;
    x0i = x0i < 0 ? 0 : (x0i > 127 ? 127 : x0i);
    const int x1i = (x0i + 1 > 127) ? 127 : x0i + 1;
    const float4 s0 = ((const float4*)(xb + (((yy << 7) + x0i) << 6)))[c4];
    const float4 s1 = ((const float4*)(xb + (((yy << 7) + x1i) << 6)))[c4];
    const float w0 = 1.0f - w1;
    const int boff = (pix * 1152 + tap * 128 + c4 * 8) ^ ((pix & 7) << 4);
    uint2 pk;
    pk.x = (unsigned)f2bf(s0.x * w0 + s1.x * w1) |
           ((unsigned)f2bf(s0.y * w0 + s1.y * w1) << 16);
    pk.y = (unsigned)f2bf(s0.z * w0 + s1.z * w1) |
           ((unsigned)f2bf(s0.w * w0 + s1.w * w1) << 16);
    *(uint2*)(lds + boff) = pk;
  }
  __syncthreads();

  const int m = wv & 1;
  const int f0 = (wv >> 1) << 5;
  const int colf = lane & 15;
  const int q4 = lane >> 4;
  const int pixr = m * 16 + colf;
  f32x4 a0 = {0.f, 0.f, 0.f, 0.f}, a1 = a0;
  for (int ks = 0; ks < 18; ++ks) {
    const int aoff = (pixr * 1152 + ks * 64 + q4 * 16) ^ ((pixr & 7) << 4);
    const short8 af = *(const short8*)(lds + aoff);
    short8 bf0, bf1;
    const float* wp = cW + (size_t)(ks * 32 + q4 * 8) * 128 + f0 + colf;
#pragma unroll
    for (int jj = 0; jj < 8; ++jj) bf0[jj] = (short)f2bf(wp[jj * 128]);
#pragma unroll
    for (int jj = 0; jj < 8; ++jj) bf1[jj] = (short)f2bf(wp[jj * 128 + 16]);
    a0 = __builtin_amdgcn_mfma_f32_16x16x32_bf16(bf0, af, a0, 0, 0, 0);
    a1 = __builtin_amdgcn_mfma_f32_16x16x32_bf16(bf1, af, a1, 0, 0, 0);
  }

  const float cb0s = cb[f0 + colf];
  const float cb1s = cb[f0 + 16 + colf];
  float* obase = out + (((size_t)((b << 14) | (i << 7) | j0)) << 7);
#pragma unroll
  for (int reg = 0; reg < 4; ++reg) {
    float* r = obase + (size_t)(m * 16 + q4 * 4 + reg) * 128;
    r[f0 + colf] = a0[reg] + cb0s;
    r[f0 + 16 + colf] = a1[reg] + cb1s;
  }
}

extern "C" void kernel_launch(void* const* d_in, const int* in_sizes, int n_in,
                              void* d_out, int out_size, void* d_ws, size_t ws_size,
                              hipStream_t stream) {
  const float* x = (const float*)d_in[0];
  const float* oW = (const float*)d_in[1];
  const float* ob = (const float*)d_in[2];
  const float* cW = (const float*)d_in[3];
  const float* cb = (const float*)d_in[4];
  float* out = (float*)d_out;

  if (ws_size >= WS_SPLIT) {
    unsigned short* cWb = (unsigned short*)d_ws;
    float* offs = (float*)((char*)d_ws + OFFS_OFF);
    hipLaunchKernelGGL(pack_weights, dim3(288), dim3(256), 0, stream, cW, cWb);
    hipLaunchKernelGGL(offsets_kernel, dim3(512), dim3(256), 0, stream,
                       x, oW, ob, offs);
    hipLaunchKernelGGL(main_kernel, dim3(4096), dim3(512), 0, stream,
                       x, offs, cb, out, cWb);
  } else {
    hipLaunchKernelGGL(fused_deform_kernel, dim3(4096), dim3(512), 0, stream,
                       x, oW, ob, cW, cb, out);
  }
}